// Round 6
// baseline (239.845 us; speedup 1.0000x reference)
//
#include <hip/hip_runtime.h>
#include <hip/hip_fp16.h>

// Problem constants (B,C,H,W = 2,3,96,96; D=32)
#define BB 2
#define CC 3
#define NN 9216   // 96*96
#define DD 32
#define NSPLIT 8                      // waves per block, split over keys
#define KEYS_PER_WAVE (NN / NSPLIT)   // 1152
#define CHUNKS (KEYS_PER_WAVE / 64)   // 18
#define L2E 1.44269504f

typedef _Float16 half8 __attribute__((ext_vector_type(8)));
typedef _Float16 half4v __attribute__((ext_vector_type(4)));
typedef __fp16 fp16x2 __attribute__((ext_vector_type(2)));
typedef float float4v __attribute__((ext_vector_type(4)));

#define MFMA16(a, b, c) __builtin_amdgcn_mfma_f32_16x16x32_f16((a), (b), (c), 0, 0, 0)

// ---------------------------------------------------------------------------
// Fused prep. Blocks [0,288): QK — thread per (b, n, part), part = 8 channels
// of both f and g, hi/lo split. QUERY IS PRE-SCALED BY log2(e) so the QK^T
// MFMA emits scores directly in the log2 domain (saves 16 v_fma/chunk in the
// attention hot loop). Blocks [288,576): V — [B][D][N] fp16, 16B stores.
// ---------------------------------------------------------------------------
__global__ __launch_bounds__(256) void prep_kernel(
    const float* __restrict__ img,
    const float* __restrict__ kw, const float* __restrict__ kb,
    const float* __restrict__ qw, const float* __restrict__ qb,
    const float* __restrict__ vw, const float* __restrict__ vb,
    _Float16* __restrict__ fH, _Float16* __restrict__ fL,
    _Float16* __restrict__ gH, _Float16* __restrict__ gL,
    _Float16* __restrict__ hV)
{
    int bid = blockIdx.x;
    if (bid < 288) {
        int id = bid * 256 + threadIdx.x;          // [0, BB*NN*4)
        int part = id & 3;
        int n = (id >> 2) % NN;
        int b = (id >> 2) / NN;
        const float* xb = img + (size_t)b * CC * NN + n;
        float x0 = xb[0], x1 = xb[NN], x2 = xb[2 * NN];
        half8 fh, fl, gh, gl;
#pragma unroll
        for (int j = 0; j < 8; j++) {
            int d = part * 8 + j;
            float fv = kw[d * 3 + 0] * x0 + kw[d * 3 + 1] * x1 + kw[d * 3 + 2] * x2 + kb[d];
            float gv = (qw[d * 3 + 0] * x0 + qw[d * 3 + 1] * x1 + qw[d * 3 + 2] * x2 + qb[d]) * L2E;
            _Float16 fhi = (_Float16)fv;
            _Float16 ghi = (_Float16)gv;
            fh[j] = fhi; fl[j] = (_Float16)(fv - (float)fhi);
            gh[j] = ghi; gl[j] = (_Float16)(gv - (float)ghi);
        }
        size_t off = ((size_t)b * NN + n) * DD + part * 8;
        *(half8*)(fH + off) = fh;
        *(half8*)(fL + off) = fl;
        *(half8*)(gH + off) = gh;
        *(half8*)(gL + off) = gl;
    } else {
        int id = (bid - 288) * 256 + threadIdx.x;  // [0, BB*DD*NN/8)
        const int N8 = NN / 8;
        int n8 = id % N8;
        int d = (id / N8) % DD;
        int b = id / (N8 * DD);
        const float* xb = img + (size_t)b * CC * NN + n8 * 8;
        float w0 = vw[d * 3 + 0], w1 = vw[d * 3 + 1], w2 = vw[d * 3 + 2], bv = vb[d];
        half8 hv;
#pragma unroll
        for (int j = 0; j < 8; j++)
            hv[j] = (_Float16)(w0 * xb[j] + w1 * xb[NN + j] + w2 * xb[2 * NN + j] + bv);
        *(half8*)(hV + (size_t)id * 8) = hv;
    }
}

// ---------------------------------------------------------------------------
// Flash attention, split-K x8, software-pipelined:
//   - K fragments prefetched one chunk ahead (explicit 2-stage pipeline);
//     V fragments issued at chunk top, consumed ~300 cyc later at PV.
//   - NO full memory fences in the loop (R4's clobbers serialized all memory
//     ops). P write->read ordering through LDS is guaranteed by per-thread
//     alias overlap + in-order per-wave DS; wave_barrier() pins scheduling.
//   - Softmax fully in log2 domain (Q pre-scaled by log2e at prep).
//   - launch_bounds(512,4): trade occupancy cap (16 waves/CU, measured to be
//     plentiful — R2->R4 TLP was a wash) for 128-VGPR pipeline depth.
// ---------------------------------------------------------------------------
__global__ __launch_bounds__(512, 4) void attn_kernel(
    const _Float16* __restrict__ fH, const _Float16* __restrict__ fL,
    const _Float16* __restrict__ gH, const _Float16* __restrict__ gL,
    const _Float16* __restrict__ hV,
    const float* __restrict__ ow, const float* __restrict__ ob,
    float* __restrict__ out)
{
    const int tile = blockIdx.x;           // 0 .. B*(N/16)-1
    const int b = tile / (NN / 16);
    const int m0 = (tile % (NN / 16)) * 16;
    const int tid = threadIdx.x;
    const int w = tid >> 6;                // wave id 0..7
    const int lane = tid & 63;
    const int l16 = lane & 15;
    const int quad = lane >> 4;

    __shared__ __align__(16) _Float16 Plds[NSPLIT][16 * 72];
    __shared__ float accbuf[NSPLIT][16][33];
    __shared__ float mbuf[NSPLIT][16];
    __shared__ float lbuf[NSPLIT][16];
    __shared__ float vlds[16 * 33];

    // Q B-fragments (hi + lo, log2e-scaled): B[k=quad*8+j][col=m=l16]
    half8 qh = *(const half8*)(gH + ((size_t)b * NN + m0 + l16) * DD + quad * 8);
    half8 ql = *(const half8*)(gL + ((size_t)b * NN + m0 + l16) * DD + quad * 8);

    float4v acc0 = {0.f, 0.f, 0.f, 0.f};  // O[m=quad*4+r][d=l16]
    float4v acc1 = {0.f, 0.f, 0.f, 0.f};  // O[m=quad*4+r][d=l16+16]
    float mrun = -1e30f, lrun = 0.f;      // per-lane stats (log2 domain)

    const int nbase = w * KEYS_PER_WAVE;
    const _Float16* hb = hV + (size_t)b * DD * NN;
    const _Float16* vp0 = hb + (size_t)l16 * NN + nbase + quad * 8;
    const _Float16* vp1 = hb + (size_t)(l16 + 16) * NN + nbase + quad * 8;
    const _Float16* khp = fH + ((size_t)b * NN + nbase + l16) * DD + quad * 8;
    const _Float16* klp = fL + ((size_t)b * NN + nbase + l16) * DD + quad * 8;
    _Float16* Pw = &Plds[w][0];

    // ---- pipeline prologue: chunk-0 K fragments
    half8 ka[4], kl[4];
#pragma unroll
    for (int blk = 0; blk < 4; blk++) {
        ka[blk] = *(const half8*)(khp + (size_t)blk * 16 * DD);
        kl[blk] = *(const half8*)(klp + (size_t)blk * 16 * DD);
    }

#pragma unroll 2
    for (int c = 0; c < CHUNKS; ++c) {
        // ---- V fragments for THIS chunk (consumed at PV, ~300 cyc of slack)
        half8 v00 = *(const half8*)(vp0 + c * 64);
        half8 v01 = *(const half8*)(vp0 + c * 64 + 32);
        half8 v10 = *(const half8*)(vp1 + c * 64);
        half8 v11 = *(const half8*)(vp1 + c * 64 + 32);
        // ---- prefetch NEXT chunk's K fragments (clamped on last iteration)
        int cn = (c + 1 < CHUNKS) ? (c + 1) : (CHUNKS - 1);
        half8 nka[4], nkl[4];
#pragma unroll
        for (int blk = 0; blk < 4; blk++) {
            nka[blk] = *(const half8*)(khp + (size_t)(cn * 64 + blk * 16) * DD);
            nkl[blk] = *(const half8*)(klp + (size_t)(cn * 64 + blk * 16) * DD);
        }
        // ---- scores (log2 domain): A = K (rows n), B = Q*log2e (cols m)
        float4v s[4];
#pragma unroll
        for (int blk = 0; blk < 4; blk++) {
            float4v z = {0.f, 0.f, 0.f, 0.f};
            float4v t = MFMA16(ka[blk], ql, z);
            t = MFMA16(kl[blk], qh, t);
            s[blk] = MFMA16(ka[blk], qh, t);
        }
        // ---- max over 64 keys: local tree + 2 cross-quad shuffles
        float mb0 = fmaxf(fmaxf(s[0][0], s[0][1]), fmaxf(s[0][2], s[0][3]));
        float mb1 = fmaxf(fmaxf(s[1][0], s[1][1]), fmaxf(s[1][2], s[1][3]));
        float mb2 = fmaxf(fmaxf(s[2][0], s[2][1]), fmaxf(s[2][2], s[2][3]));
        float mb3 = fmaxf(fmaxf(s[3][0], s[3][1]), fmaxf(s[3][2], s[3][3]));
        float mx = fmaxf(fmaxf(mb0, mb1), fmaxf(mb2, mb3));
        mx = fmaxf(mx, __shfl_xor(mx, 16, 64));
        mx = fmaxf(mx, __shfl_xor(mx, 32, 64));
        float mnew = fmaxf(mrun, mx);
        // ---- P = exp2(s - mnew); per-blk exp/pack/sum (short liveness)
        half4v pv[4];
        float r0, r1, r2, r3;
#pragma unroll
        for (int blk = 0; blk < 4; blk++) {
            float p0 = __builtin_amdgcn_exp2f(s[blk][0] - mnew);
            float p1 = __builtin_amdgcn_exp2f(s[blk][1] - mnew);
            float p2 = __builtin_amdgcn_exp2f(s[blk][2] - mnew);
            float p3 = __builtin_amdgcn_exp2f(s[blk][3] - mnew);
            union { fp16x2 h2[2]; half4v h4; } u;
            u.h2[0] = __builtin_amdgcn_cvt_pkrtz(p0, p1);
            u.h2[1] = __builtin_amdgcn_cvt_pkrtz(p2, p3);
            pv[blk] = u.h4;
            float rs = (p0 + p1) + (p2 + p3);
            if (blk == 0) r0 = rs; else if (blk == 1) r1 = rs;
            else if (blk == 2) r2 = rs; else r3 = rs;
        }
        float rsum = (r0 + r1) + (r2 + r3);
        rsum += __shfl_xor(rsum, 16, 64);
        rsum += __shfl_xor(rsum, 32, 64);
        // ---- rescale accumulators only when the max moved (wave-collective)
        if (__any(mnew > mrun)) {
            float alpha = __builtin_amdgcn_exp2f(mrun - mnew);
            float aT[4];
#pragma unroll
            for (int r = 0; r < 4; r++) aT[r] = __shfl(alpha, quad * 4 + r, 64);
#pragma unroll
            for (int r = 0; r < 4; r++) { acc0[r] *= aT[r]; acc1[r] *= aT[r]; }
            lrun = lrun * alpha + rsum;
            mrun = mnew;
        } else {
            lrun += rsum;
        }
        // ---- stage P: [m=l16][n = blk*16 + quad*4 + r], packed 8B writes
#pragma unroll
        for (int blk = 0; blk < 4; blk++)
            *(half4v*)(Pw + l16 * 72 + blk * 16 + quad * 4) = pv[blk];
        __builtin_amdgcn_wave_barrier();   // pin write->read scheduling (no fence)
        // ---- PV: A = P[m][n] (b128 from LDS), B = V[n][d]
        half8 pf0 = *(const half8*)(Pw + l16 * 72 + quad * 8);
        half8 pf1 = *(const half8*)(Pw + l16 * 72 + 32 + quad * 8);
        acc0 = MFMA16(pf0, v00, acc0);
        acc1 = MFMA16(pf0, v10, acc1);
        acc0 = MFMA16(pf1, v01, acc0);
        acc1 = MFMA16(pf1, v11, acc1);
        __builtin_amdgcn_wave_barrier();   // reads before next chunk's writes
        // ---- rotate pipeline registers
#pragma unroll
        for (int blk = 0; blk < 4; blk++) { ka[blk] = nka[blk]; kl[blk] = nkl[blk]; }
    }

    // ---- write per-wave partials (fp32) for the split-K merge
    mbuf[w][l16] = mrun;                  // redundant across quads, same value
    lbuf[w][l16] = lrun;
#pragma unroll
    for (int r = 0; r < 4; r++) {
        accbuf[w][quad * 4 + r][l16]      = acc0[r];
        accbuf[w][quad * 4 + r][l16 + 16] = acc1[r];
    }
    __syncthreads();

    // ---- merge 8 waves: 512 (m,d) elems, one per thread (log2 domain)
    {
        int m = tid >> 5, d = tid & 31;
        float M = mbuf[0][m];
#pragma unroll
        for (int s2 = 1; s2 < NSPLIT; s2++) M = fmaxf(M, mbuf[s2][m]);
        float L = 0.f, num = 0.f;
#pragma unroll
        for (int s2 = 0; s2 < NSPLIT; s2++) {
            float e = __builtin_amdgcn_exp2f(mbuf[s2][m] - M);
            L += lbuf[s2][m] * e;
            num += accbuf[s2][m][d] * e;
        }
        vlds[m * 33 + d] = num / L;
    }
    __syncthreads();

    // ---- epilogue: D->3 projection + clamp (48 threads)
    if (tid < 48) {
        int m = tid & 15, c = tid >> 4;
        float o = ob[c];
#pragma unroll
        for (int d = 0; d < DD; d++)
            o += ow[c * DD + d] * vlds[m * 33 + d];
        o = fminf(1.f, fmaxf(-1.f, o));
        out[((size_t)b * CC + c) * NN + m0 + m] = o;
    }
}

extern "C" void kernel_launch(void* const* d_in, const int* in_sizes, int n_in,
                              void* d_out, int out_size, void* d_ws, size_t ws_size,
                              hipStream_t stream) {
    const float* img = (const float*)d_in[0];
    const float* kw  = (const float*)d_in[1];
    const float* kb  = (const float*)d_in[2];
    const float* qw  = (const float*)d_in[3];
    const float* qb  = (const float*)d_in[4];
    const float* vw  = (const float*)d_in[5];
    const float* vb  = (const float*)d_in[6];
    const float* ow  = (const float*)d_in[7];
    const float* ob  = (const float*)d_in[8];
    float* out = (float*)d_out;

    // Workspace: fH,fL,gH,gL ([B][N][D] fp16) + hV ([B][D][N] fp16) = 5.9 MB
    const size_t sz = (size_t)BB * NN * DD;
    _Float16* fH = (_Float16*)d_ws;
    _Float16* fL = fH + sz;
    _Float16* gH = fL + sz;
    _Float16* gL = gH + sz;
    _Float16* hV = gL + sz;

    prep_kernel<<<576, 256, 0, stream>>>(img, kw, kb, qw, qb, vw, vb, fH, fL, gH, gL, hV);
    attn_kernel<<<BB * (NN / 16), 512, 0, stream>>>(fH, fL, gH, gL, hV, ow, ob, out);
}